// Round 1
// baseline (157.422 us; speedup 1.0000x reference)
//
#include <hip/hip_runtime.h>

using f16   = _Float16;
using f16x4 = __attribute__((ext_vector_type(4))) _Float16;
using f16x8 = __attribute__((ext_vector_type(8))) _Float16;
using f32x4 = __attribute__((ext_vector_type(4))) float;

#define BDIM 4
#define EDIM 512
#define LDIM 512
#define VDIM 32000
#define RDIM 2048            // B*L
#define INV_TAU 0.1f

using gcvoid = const __attribute__((address_space(1))) void;
using lvoid  = __attribute__((address_space(3))) void;

__device__ __forceinline__ void gload_lds16(const void* g, void* l) {
  __builtin_amdgcn_global_load_lds((gcvoid*)g, (lvoid*)l, 16, 0, 0);
}

// ---------------- kernel 1: DE [B,E,L] f32 -> A16 [R=B*L][E] f16 (transpose+convert)
__global__ void cvtA_kernel(const float* __restrict__ DE, f16* __restrict__ A16) {
  __shared__ float tile[64][65];            // +1 pad: conflict-free column reads
  const int b  = blockIdx.z;
  const int e0 = blockIdx.y * 64;
  const int l0 = blockIdx.x * 64;
  const int t  = threadIdx.x;
#pragma unroll
  for (int i = 0; i < 4; ++i) {
    int idx = t + i * 256;                  // 1024 float4 slots
    int el  = idx >> 4;                     // e-local 0..63
    int l4  = (idx & 15) * 4;               // l-local chunk
    float4 v = *reinterpret_cast<const float4*>(
        DE + (size_t)(b * 512 + e0 + el) * 512 + l0 + l4);
    tile[el][l4 + 0] = v.x;
    tile[el][l4 + 1] = v.y;
    tile[el][l4 + 2] = v.z;
    tile[el][l4 + 3] = v.w;
  }
  __syncthreads();
#pragma unroll
  for (int i = 0; i < 4; ++i) {
    int idx = t + i * 256;
    int ll  = idx >> 4;                     // l-local 0..63
    int e4  = (idx & 15) * 4;               // e-local chunk
    f16x4 h;
    h[0] = (f16)tile[e4 + 0][ll];
    h[1] = (f16)tile[e4 + 1][ll];
    h[2] = (f16)tile[e4 + 2][ll];
    h[3] = (f16)tile[e4 + 3][ll];
    *reinterpret_cast<f16x4*>(A16 + (size_t)(b * 512 + l0 + ll) * 512 + e0 + e4) = h;
  }
}

// ---------------- kernel 2: M [V,E] f32 -> B16 [V][E] f16 (stream convert)
__global__ void cvtM_kernel(const float* __restrict__ M, f16* __restrict__ B16) {
  const size_t N4 = (size_t)VDIM * EDIM / 4;
  const size_t stride = (size_t)gridDim.x * blockDim.x;
  for (size_t i = (size_t)blockIdx.x * blockDim.x + threadIdx.x; i < N4; i += stride) {
    float4 v = reinterpret_cast<const float4*>(M)[i];
    f16x4 h = { (f16)v.x, (f16)v.y, (f16)v.z, (f16)v.w };
    reinterpret_cast<f16x4*>(B16)[i] = h;
  }
}

// ---------------- kernel 3: fused GEMM + exp + vocab-sum
// C[r][v] = sum_k A16[r][k]*B16[v][k]; down[r] += sum_v exp(C[r][v]/tau)
// 128x128 tile, BK=64, 4 waves (2x2 of 64x64), global_load_lds(16B) with
// pre-swizzled global src; LDS rows 128B, XOR-swizzle byte ^= (row&7)<<4.
__global__ __launch_bounds__(256, 2) void gemm_kernel(const f16* __restrict__ A16,
                                                      const f16* __restrict__ B16,
                                                      float* __restrict__ down) {
  __shared__ __align__(16) char smA[2][16384];
  __shared__ __align__(16) char smB[2][16384];
  const int bid = blockIdx.x;
  const int rt  = bid & 15;                 // 16 row tiles (fast: share B panel)
  const int ct  = bid >> 4;                 // 250 col tiles
  const int r0  = rt * 128, c0 = ct * 128;
  const int tid  = threadIdx.x;
  const int lane = tid & 63;
  const int w    = tid >> 6;
  const int wr   = w >> 1, wc = w & 1;
  const int srow   = lane >> 3;             // 0..7 within one 1KB instr
  const int schunk = lane & 7;              // 16B chunk within 128B row

  auto stage = [&](int buf, int kt) {
    const int kbase = kt * 64;
#pragma unroll
    for (int i = 0; i < 4; ++i) {
      int instr = w * 4 + i;                // 16 instrs cover 128 rows
      int row = instr * 8 + srow;
      int c = schunk ^ (row & 7);           // inverse-swizzled source chunk
      gload_lds16(A16 + (size_t)(r0 + row) * 512 + kbase + c * 8,
                  &smA[buf][instr * 1024]);
      gload_lds16(B16 + (size_t)(c0 + row) * 512 + kbase + c * 8,
                  &smB[buf][instr * 1024]);
    }
  };

  f32x4 acc[4][4] = {};
  stage(0, 0);
  int cur = 0;
  const int hi16 = (lane >> 4) * 16;        // k-group byte offset
  for (int kt = 0; kt < 8; ++kt) {
    __syncthreads();                        // drains vmcnt: buf[cur] ready
    if (kt < 7) stage(cur ^ 1, kt + 1);
    f16x8 af[2][4], bf[2][4];
#pragma unroll
    for (int mi = 0; mi < 4; ++mi) {
      int row = wr * 64 + mi * 16 + (lane & 15);
      int sw  = (row & 7) << 4;
#pragma unroll
      for (int kk = 0; kk < 2; ++kk)
        af[kk][mi] = *reinterpret_cast<const f16x8*>(
            &smA[cur][row * 128 + ((kk * 64 + hi16) ^ sw)]);
    }
#pragma unroll
    for (int ni = 0; ni < 4; ++ni) {
      int col = wc * 64 + ni * 16 + (lane & 15);
      int sw  = (col & 7) << 4;
#pragma unroll
      for (int kk = 0; kk < 2; ++kk)
        bf[kk][ni] = *reinterpret_cast<const f16x8*>(
            &smB[cur][col * 128 + ((kk * 64 + hi16) ^ sw)]);
    }
#pragma unroll
    for (int kk = 0; kk < 2; ++kk)
#pragma unroll
      for (int mi = 0; mi < 4; ++mi)
#pragma unroll
        for (int ni = 0; ni < 4; ++ni)
          acc[mi][ni] = __builtin_amdgcn_mfma_f32_16x16x32_f16(
              af[kk][mi], bf[kk][ni], acc[mi][ni], 0, 0, 0);
    cur ^= 1;
  }

  // epilogue: exp + sum over this wave's 64 columns, then atomic into down[]
  // D layout: col = lane&15, row = (lane>>4)*4 + j  (m89-verified)
  const int rbase = r0 + wr * 64;
#pragma unroll
  for (int mi = 0; mi < 4; ++mi) {
    float s0 = 0.f, s1 = 0.f, s2 = 0.f, s3 = 0.f;
#pragma unroll
    for (int ni = 0; ni < 4; ++ni) {
      f32x4 v = acc[mi][ni];
      s0 += __expf(INV_TAU * v[0]);
      s1 += __expf(INV_TAU * v[1]);
      s2 += __expf(INV_TAU * v[2]);
      s3 += __expf(INV_TAU * v[3]);
    }
#pragma unroll
    for (int m = 1; m <= 8; m <<= 1) {      // reduce across 16 cols (lane&15)
      s0 += __shfl_xor(s0, m);
      s1 += __shfl_xor(s1, m);
      s2 += __shfl_xor(s2, m);
      s3 += __shfl_xor(s3, m);
    }
    if ((lane & 15) == 0) {
      int row = rbase + mi * 16 + (lane >> 4) * 4;
      atomicAdd(&down[row + 0], s0);
      atomicAdd(&down[row + 1], s1);
      atomicAdd(&down[row + 2], s2);
      atomicAdd(&down[row + 3], s3);
    }
  }
}

// ---------------- kernel 4: up = exp(EN.DE/tau); out += up/down  (fp32 exact)
__global__ void finalize_kernel(const float* __restrict__ EN, const float* __restrict__ DE,
                                const float* __restrict__ down, float* __restrict__ out) {
  __shared__ float red[4][64];
  const int r0 = blockIdx.x * 64;           // 32 blocks x 64 rows
  const int b  = r0 >> 9;
  const int l0 = r0 & 511;
  const int t  = threadIdx.x;
  const int ll = t & 63;
  const int g  = t >> 6;                    // 4 e-chunks of 128
  float p = 0.f;
  const int ebase = g * 128;
#pragma unroll 4
  for (int e = 0; e < 128; ++e) {
    size_t idx = (size_t)(b * 512 + ebase + e) * 512 + l0 + ll;
    p += EN[idx] * DE[idx];
  }
  red[g][ll] = p;
  __syncthreads();
  if (t < 64) {
    float s = red[0][t] + red[1][t] + red[2][t] + red[3][t];
    float val = __expf(INV_TAU * s) / down[r0 + t];
#pragma unroll
    for (int m = 1; m <= 32; m <<= 1) val += __shfl_xor(val, m);
    if (t == 0) atomicAdd(out, val);
  }
}

extern "C" void kernel_launch(void* const* d_in, const int* in_sizes, int n_in,
                              void* d_out, int out_size, void* d_ws, size_t ws_size,
                              hipStream_t stream) {
  const float* EN = (const float*)d_in[0];
  const float* DE = (const float*)d_in[1];
  const float* M  = (const float*)d_in[2];

  // ws layout: down[2048] f32 | A16 [2048*512] f16 | B16 [32000*512] f16
  float* down = (float*)d_ws;
  f16* A16 = (f16*)((char*)d_ws + 8192);
  f16* B16 = (f16*)((char*)d_ws + 8192 + (size_t)RDIM * EDIM * 2);
  const size_t need = 8192 + (size_t)RDIM * EDIM * 2 + (size_t)VDIM * EDIM * 2;

  hipMemsetAsync(d_out, 0, sizeof(float), stream);
  if (ws_size < need) return;               // out stays 0 -> diagnosable fail
  hipMemsetAsync(d_ws, 0, RDIM * sizeof(float), stream);

  cvtA_kernel<<<dim3(8, 8, 4), 256, 0, stream>>>(DE, A16);
  cvtM_kernel<<<2048, 256, 0, stream>>>(M, B16);
  gemm_kernel<<<4000, 256, 0, stream>>>(A16, B16, down);
  finalize_kernel<<<32, 256, 0, stream>>>(EN, DE, down, (float*)d_out);
}

// Round 2
// 128.791 us; speedup vs baseline: 1.2223x; 1.2223x over previous
//
#include <hip/hip_runtime.h>

using f16   = _Float16;
using f16x4 = __attribute__((ext_vector_type(4))) _Float16;
using f16x8 = __attribute__((ext_vector_type(8))) _Float16;
using f32x4 = __attribute__((ext_vector_type(4))) float;

#define BDIM 4
#define EDIM 512
#define LDIM 512
#define VDIM 32000
#define RDIM 2048            // B*L
#define INV_TAU 0.1f

using gcvoid = const __attribute__((address_space(1))) void;
using lvoid  = __attribute__((address_space(3))) void;

__device__ __forceinline__ void gload_lds16(const void* g, void* l) {
  __builtin_amdgcn_global_load_lds((gcvoid*)g, (lvoid*)l, 16, 0, 0);
}

// ---------------- kernel 1: DE [B,E,L] f32 -> A16 [R=B*L][E] f16 (transpose+convert)
__global__ void cvtA_kernel(const float* __restrict__ DE, f16* __restrict__ A16) {
  __shared__ float tile[64][65];
  const int b  = blockIdx.z;
  const int e0 = blockIdx.y * 64;
  const int l0 = blockIdx.x * 64;
  const int t  = threadIdx.x;
#pragma unroll
  for (int i = 0; i < 4; ++i) {
    int idx = t + i * 256;
    int el  = idx >> 4;
    int l4  = (idx & 15) * 4;
    float4 v = *reinterpret_cast<const float4*>(
        DE + (size_t)(b * 512 + e0 + el) * 512 + l0 + l4);
    tile[el][l4 + 0] = v.x;
    tile[el][l4 + 1] = v.y;
    tile[el][l4 + 2] = v.z;
    tile[el][l4 + 3] = v.w;
  }
  __syncthreads();
#pragma unroll
  for (int i = 0; i < 4; ++i) {
    int idx = t + i * 256;
    int ll  = idx >> 4;
    int e4  = (idx & 15) * 4;
    f16x4 h;
    h[0] = (f16)tile[e4 + 0][ll];
    h[1] = (f16)tile[e4 + 1][ll];
    h[2] = (f16)tile[e4 + 2][ll];
    h[3] = (f16)tile[e4 + 3][ll];
    *reinterpret_cast<f16x4*>(A16 + (size_t)(b * 512 + l0 + ll) * 512 + e0 + e4) = h;
  }
}

// ---------------- kernel 2: M [V,E] f32 -> B16 [V][E] f16 (stream convert)
__global__ void cvtM_kernel(const float* __restrict__ M, f16* __restrict__ B16) {
  const size_t N4 = (size_t)VDIM * EDIM / 4;
  const size_t stride = (size_t)gridDim.x * blockDim.x;
  for (size_t i = (size_t)blockIdx.x * blockDim.x + threadIdx.x; i < N4; i += stride) {
    float4 v = reinterpret_cast<const float4*>(M)[i];
    f16x4 h = { (f16)v.x, (f16)v.y, (f16)v.z, (f16)v.w };
    reinterpret_cast<f16x4*>(B16)[i] = h;
  }
}

// ---------------- kernel 3: fused GEMM + exp + vocab-sum, counted-vmcnt pipeline
// C[r][v] = sum_k A16[r][k]*B16[v][k]; down[r] += sum_v exp(C[r][v]/tau)
// 128x128 tile, BK=32, 16 K-tiles, 4-deep LDS ring (4 x 16KB), 4 waves.
// Per iter: ds_read 8 frags (contiguous 1KB each, conflict-free, no swizzle),
// stage K-tile t+3 (4 x global_load_lds, linear dest), 16 MFMA,
// s_waitcnt vmcnt(8) lgkmcnt(0) + raw s_barrier (never drain vmcnt to 0).
__global__ __launch_bounds__(256, 2) void gemm_kernel(const f16* __restrict__ A16,
                                                      const f16* __restrict__ B16,
                                                      float* __restrict__ down) {
  __shared__ __align__(16) char sm[4][16384];   // per buf: A[128][32] f16 | B[128][32] f16
  const int orig = blockIdx.x;                  // 4000 blocks = 8 * 500 (bijective)
  const int bid  = (orig & 7) * 500 + (orig >> 3);
  const int rt   = bid & 15;                    // 16 row tiles
  const int ct   = bid >> 4;                    // 250 col tiles
  const int r0   = rt * 128, c0 = ct * 128;
  const int tid  = threadIdx.x;
  const int lane = tid & 63;
  const int w    = tid >> 6;
  const int wr   = w >> 1, wc = w & 1;

  // staging: lane l of instr covers LDS bytes instr*1024 + l*16
  //   -> row = instr*16 + (l>>2), elem = (l&3)*8   (row stride 64B)
  const int srow = lane >> 2;                   // row within 16-row group... (l>>2)
  const int sel  = (lane & 3) * 8;

  auto stage = [&](int buf, int t) {
    const int kbase = t * 32;
#pragma unroll
    for (int i = 0; i < 2; ++i) {
      int instr = w * 2 + i;                    // 8 instrs cover 128 rows
      gload_lds16(A16 + (size_t)(r0 + instr * 16 + srow) * 512 + kbase + sel,
                  &sm[buf][instr * 1024]);
    }
#pragma unroll
    for (int i = 0; i < 2; ++i) {
      int instr = w * 2 + i;
      gload_lds16(B16 + (size_t)(c0 + instr * 16 + srow) * 512 + kbase + sel,
                  &sm[buf][8192 + instr * 1024]);
    }
  };

  f32x4 acc[4][4] = {};

  // prologue: fill 3 ring slots (12 loads/wave), wait K0 (oldest 4) landed
  stage(0, 0);
  stage(1, 1);
  stage(2, 2);
  asm volatile("s_waitcnt vmcnt(8)" ::: "memory");
  __builtin_amdgcn_s_barrier();
  asm volatile("" ::: "memory");

  const int koff = (lane >> 4) * 16;            // 8-elem k-group byte offset
  const int arow = (wr * 64 + (lane & 15)) * 64;
  const int brow = (wc * 64 + (lane & 15)) * 64;

#pragma unroll
  for (int t = 0; t < 16; ++t) {
    const int cur = t & 3;
    f16x8 af[4], bf[4];
#pragma unroll
    for (int mi = 0; mi < 4; ++mi)
      af[mi] = *reinterpret_cast<const f16x8*>(&sm[cur][arow + mi * 1024 + koff]);
#pragma unroll
    for (int ni = 0; ni < 4; ++ni)
      bf[ni] = *reinterpret_cast<const f16x8*>(&sm[cur][8192 + brow + ni * 1024 + koff]);

    if (t + 3 < 16) stage((t + 3) & 3, t + 3);

    __builtin_amdgcn_s_setprio(1);
#pragma unroll
    for (int mi = 0; mi < 4; ++mi)
#pragma unroll
      for (int ni = 0; ni < 4; ++ni)
        acc[mi][ni] = __builtin_amdgcn_mfma_f32_16x16x32_f16(
            af[mi], bf[ni], acc[mi][ni], 0, 0, 0);
    __builtin_amdgcn_s_setprio(0);

    if (t < 15) {
      // counted wait: allow last 2 K-tiles' stagings (8 loads) in flight;
      // guarantees K(t+1) landed. lgkmcnt(0) closes the ring-slot WAR hazard.
      if (t <= 12)      asm volatile("s_waitcnt vmcnt(8) lgkmcnt(0)" ::: "memory");
      else if (t == 13) asm volatile("s_waitcnt vmcnt(4) lgkmcnt(0)" ::: "memory");
      else              asm volatile("s_waitcnt vmcnt(0) lgkmcnt(0)" ::: "memory");
      __builtin_amdgcn_s_barrier();
      asm volatile("" ::: "memory");
    }
  }

  // epilogue: exp + sum over this wave's 64 columns, then atomic into down[]
  // D layout: col = lane&15, row = (lane>>4)*4 + j  (m89-verified)
  const int rbase = r0 + wr * 64;
#pragma unroll
  for (int mi = 0; mi < 4; ++mi) {
    float s0 = 0.f, s1 = 0.f, s2 = 0.f, s3 = 0.f;
#pragma unroll
    for (int ni = 0; ni < 4; ++ni) {
      f32x4 v = acc[mi][ni];
      s0 += __expf(INV_TAU * v[0]);
      s1 += __expf(INV_TAU * v[1]);
      s2 += __expf(INV_TAU * v[2]);
      s3 += __expf(INV_TAU * v[3]);
    }
#pragma unroll
    for (int m = 1; m <= 8; m <<= 1) {
      s0 += __shfl_xor(s0, m);
      s1 += __shfl_xor(s1, m);
      s2 += __shfl_xor(s2, m);
      s3 += __shfl_xor(s3, m);
    }
    if ((lane & 15) == 0) {
      int row = rbase + mi * 16 + (lane >> 4) * 4;
      atomicAdd(&down[row + 0], s0);
      atomicAdd(&down[row + 1], s1);
      atomicAdd(&down[row + 2], s2);
      atomicAdd(&down[row + 3], s3);
    }
  }
}

// ---------------- kernel 4: up = exp(EN.DE/tau); out += up/down  (fp32 exact)
__global__ void finalize_kernel(const float* __restrict__ EN, const float* __restrict__ DE,
                                const float* __restrict__ down, float* __restrict__ out) {
  __shared__ float red[4][64];
  const int r0 = blockIdx.x * 64;
  const int b  = r0 >> 9;
  const int l0 = r0 & 511;
  const int t  = threadIdx.x;
  const int ll = t & 63;
  const int g  = t >> 6;
  float p = 0.f;
  const int ebase = g * 128;
#pragma unroll 4
  for (int e = 0; e < 128; ++e) {
    size_t idx = (size_t)(b * 512 + ebase + e) * 512 + l0 + ll;
    p += EN[idx] * DE[idx];
  }
  red[g][ll] = p;
  __syncthreads();
  if (t < 64) {
    float s = red[0][t] + red[1][t] + red[2][t] + red[3][t];
    float val = __expf(INV_TAU * s) / down[r0 + t];
#pragma unroll
    for (int m = 1; m <= 32; m <<= 1) val += __shfl_xor(val, m);
    if (t == 0) atomicAdd(out, val);
  }
}

extern "C" void kernel_launch(void* const* d_in, const int* in_sizes, int n_in,
                              void* d_out, int out_size, void* d_ws, size_t ws_size,
                              hipStream_t stream) {
  const float* EN = (const float*)d_in[0];
  const float* DE = (const float*)d_in[1];
  const float* M  = (const float*)d_in[2];

  // ws layout: down[2048] f32 | A16 [2048*512] f16 | B16 [32000*512] f16
  float* down = (float*)d_ws;
  f16* A16 = (f16*)((char*)d_ws + 8192);
  f16* B16 = (f16*)((char*)d_ws + 8192 + (size_t)RDIM * EDIM * 2);
  const size_t need = 8192 + (size_t)RDIM * EDIM * 2 + (size_t)VDIM * EDIM * 2;

  hipMemsetAsync(d_out, 0, sizeof(float), stream);
  if (ws_size < need) return;
  hipMemsetAsync(d_ws, 0, RDIM * sizeof(float), stream);

  cvtA_kernel<<<dim3(8, 8, 4), 256, 0, stream>>>(DE, A16);
  cvtM_kernel<<<2048, 256, 0, stream>>>(M, B16);
  gemm_kernel<<<4000, 256, 0, stream>>>(A16, B16, down);
  finalize_kernel<<<32, 256, 0, stream>>>(EN, DE, down, (float*)d_out);
}

// Round 3
// 125.111 us; speedup vs baseline: 1.2583x; 1.0294x over previous
//
#include <hip/hip_runtime.h>

using f16   = _Float16;
using f16x4 = __attribute__((ext_vector_type(4))) _Float16;
using f16x8 = __attribute__((ext_vector_type(8))) _Float16;
using f32x4 = __attribute__((ext_vector_type(4))) float;

#define BDIM 4
#define EDIM 512
#define LDIM 512
#define VDIM 32000
#define RDIM 2048            // B*L
#define INV_TAU 0.1f

using gcvoid = const __attribute__((address_space(1))) void;
using lvoid  = __attribute__((address_space(3))) void;

__device__ __forceinline__ void gload_lds16(const void* g, void* l) {
  __builtin_amdgcn_global_load_lds((gcvoid*)g, (lvoid*)l, 16, 0, 0);
}

// ---------------- kernel 1: DE [B,E,L] f32 -> A16 [R=B*L][E] f16 (transpose+convert)
__global__ void cvtA_kernel(const float* __restrict__ DE, f16* __restrict__ A16) {
  __shared__ float tile[64][65];
  const int b  = blockIdx.z;
  const int e0 = blockIdx.y * 64;
  const int l0 = blockIdx.x * 64;
  const int t  = threadIdx.x;
#pragma unroll
  for (int i = 0; i < 4; ++i) {
    int idx = t + i * 256;
    int el  = idx >> 4;
    int l4  = (idx & 15) * 4;
    float4 v = *reinterpret_cast<const float4*>(
        DE + (size_t)(b * 512 + e0 + el) * 512 + l0 + l4);
    tile[el][l4 + 0] = v.x;
    tile[el][l4 + 1] = v.y;
    tile[el][l4 + 2] = v.z;
    tile[el][l4 + 3] = v.w;
  }
  __syncthreads();
#pragma unroll
  for (int i = 0; i < 4; ++i) {
    int idx = t + i * 256;
    int ll  = idx >> 4;
    int e4  = (idx & 15) * 4;
    f16x4 h;
    h[0] = (f16)tile[e4 + 0][ll];
    h[1] = (f16)tile[e4 + 1][ll];
    h[2] = (f16)tile[e4 + 2][ll];
    h[3] = (f16)tile[e4 + 3][ll];
    *reinterpret_cast<f16x4*>(A16 + (size_t)(b * 512 + l0 + ll) * 512 + e0 + e4) = h;
  }
}

// ---------------- kernel 2: M [V,E] f32 -> B16 [V][E] f16 (stream convert)
__global__ void cvtM_kernel(const float* __restrict__ M, f16* __restrict__ B16) {
  const size_t N4 = (size_t)VDIM * EDIM / 4;
  const size_t stride = (size_t)gridDim.x * blockDim.x;
  for (size_t i = (size_t)blockIdx.x * blockDim.x + threadIdx.x; i < N4; i += stride) {
    float4 v = reinterpret_cast<const float4*>(M)[i];
    f16x4 h = { (f16)v.x, (f16)v.y, (f16)v.z, (f16)v.w };
    reinterpret_cast<f16x4*>(B16)[i] = h;
  }
}

// ---------------- kernel 3: fused GEMM + exp + vocab-sum, counted-vmcnt pipeline
// 128x128 tile, BK=32, 16 K-tiles, 4-deep LDS ring, 4 waves.
// LDS granule swizzle (both sides, rule #21): LDS granule g of row r holds
// global k-chunk g ^ ((r>>1)&3). Source side: sel = ((l&3)^((l>>3)&3))*8.
// Read side: koff = ((lane>>4) ^ ((lane>>1)&3))*16 (lane-constant across frags).
// Spread check: 16 lanes hit granule positions {0,4,1,5,2,6,3,7} x2 -> 2-way = free.
__global__ __launch_bounds__(256, 2) void gemm_kernel(const f16* __restrict__ A16,
                                                      const f16* __restrict__ B16,
                                                      float* __restrict__ down) {
  __shared__ __align__(16) char sm[4][16384];   // per buf: A[128][32] f16 | B[128][32] f16
  const int orig = blockIdx.x;                  // 4000 blocks = 8 * 500 (bijective)
  const int bid  = (orig & 7) * 500 + (orig >> 3);
  const int rt   = bid & 15;                    // 16 row tiles
  const int ct   = bid >> 4;                    // 250 col tiles
  const int r0   = rt * 128, c0 = ct * 128;
  const int tid  = threadIdx.x;
  const int lane = tid & 63;
  const int w    = tid >> 6;
  const int wr   = w >> 1, wc = w & 1;

  // staging: lane l of instr covers LDS bytes instr*1024 + l*16
  //   -> row = instr*16 + (l>>2); source k-granule = (l&3) ^ ((l>>3)&3)
  const int srow = lane >> 2;
  const int sel  = ((lane & 3) ^ ((lane >> 3) & 3)) * 8;   // f16 elems (x2 = bytes)

  auto stage = [&](int buf, int t) {
    const int kbase = t * 32;
#pragma unroll
    for (int i = 0; i < 2; ++i) {
      int instr = w * 2 + i;                    // 8 instrs cover 128 rows
      gload_lds16(A16 + (size_t)(r0 + instr * 16 + srow) * 512 + kbase + sel,
                  &sm[buf][instr * 1024]);
    }
#pragma unroll
    for (int i = 0; i < 2; ++i) {
      int instr = w * 2 + i;
      gload_lds16(B16 + (size_t)(c0 + instr * 16 + srow) * 512 + kbase + sel,
                  &sm[buf][8192 + instr * 1024]);
    }
  };

  f32x4 acc[4][4] = {};

  // prologue: fill 3 ring slots (12 loads/wave), wait K0 (oldest 4) landed
  stage(0, 0);
  stage(1, 1);
  stage(2, 2);
  asm volatile("s_waitcnt vmcnt(8)" ::: "memory");
  __builtin_amdgcn_s_barrier();
  asm volatile("" ::: "memory");

  // swizzled read granule: kc = lane>>4, row bits 1-2 = (lane>>1)&3
  const int koff = (((lane >> 4) ^ ((lane >> 1) & 3)) * 16);
  const int arow = (wr * 64 + (lane & 15)) * 64;
  const int brow = (wc * 64 + (lane & 15)) * 64;

#pragma unroll
  for (int t = 0; t < 16; ++t) {
    const int cur = t & 3;
    f16x8 af[4], bf[4];
#pragma unroll
    for (int mi = 0; mi < 4; ++mi)
      af[mi] = *reinterpret_cast<const f16x8*>(&sm[cur][arow + mi * 1024 + koff]);
#pragma unroll
    for (int ni = 0; ni < 4; ++ni)
      bf[ni] = *reinterpret_cast<const f16x8*>(&sm[cur][8192 + brow + ni * 1024 + koff]);

    if (t + 3 < 16) stage((t + 3) & 3, t + 3);

    __builtin_amdgcn_s_setprio(1);
#pragma unroll
    for (int mi = 0; mi < 4; ++mi)
#pragma unroll
      for (int ni = 0; ni < 4; ++ni)
        acc[mi][ni] = __builtin_amdgcn_mfma_f32_16x16x32_f16(
            af[mi], bf[ni], acc[mi][ni], 0, 0, 0);
    __builtin_amdgcn_s_setprio(0);

    if (t < 15) {
      // counted wait: allow last 2 K-tiles' stagings (8 loads) in flight;
      // guarantees K(t+1) landed. lgkmcnt(0) closes the ring-slot WAR hazard.
      if (t <= 12)      asm volatile("s_waitcnt vmcnt(8) lgkmcnt(0)" ::: "memory");
      else if (t == 13) asm volatile("s_waitcnt vmcnt(4) lgkmcnt(0)" ::: "memory");
      else              asm volatile("s_waitcnt vmcnt(0) lgkmcnt(0)" ::: "memory");
      __builtin_amdgcn_s_barrier();
      asm volatile("" ::: "memory");
    }
  }

  // epilogue: exp + sum over this wave's 64 columns, then atomic into down[]
  // D layout: col = lane&15, row = (lane>>4)*4 + j  (m89-verified)
  const int rbase = r0 + wr * 64;
#pragma unroll
  for (int mi = 0; mi < 4; ++mi) {
    float s0 = 0.f, s1 = 0.f, s2 = 0.f, s3 = 0.f;
#pragma unroll
    for (int ni = 0; ni < 4; ++ni) {
      f32x4 v = acc[mi][ni];
      s0 += __expf(INV_TAU * v[0]);
      s1 += __expf(INV_TAU * v[1]);
      s2 += __expf(INV_TAU * v[2]);
      s3 += __expf(INV_TAU * v[3]);
    }
#pragma unroll
    for (int m = 1; m <= 8; m <<= 1) {
      s0 += __shfl_xor(s0, m);
      s1 += __shfl_xor(s1, m);
      s2 += __shfl_xor(s2, m);
      s3 += __shfl_xor(s3, m);
    }
    if ((lane & 15) == 0) {
      int row = rbase + mi * 16 + (lane >> 4) * 4;
      atomicAdd(&down[row + 0], s0);
      atomicAdd(&down[row + 1], s1);
      atomicAdd(&down[row + 2], s2);
      atomicAdd(&down[row + 3], s3);
    }
  }
}

// ---------------- kernel 4: up = exp(EN.DE/tau); out += up/down  (fp32 exact)
__global__ void finalize_kernel(const float* __restrict__ EN, const float* __restrict__ DE,
                                const float* __restrict__ down, float* __restrict__ out) {
  __shared__ float red[4][64];
  const int r0 = blockIdx.x * 64;
  const int b  = r0 >> 9;
  const int l0 = r0 & 511;
  const int t  = threadIdx.x;
  const int ll = t & 63;
  const int g  = t >> 6;
  float p = 0.f;
  const int ebase = g * 128;
#pragma unroll 4
  for (int e = 0; e < 128; ++e) {
    size_t idx = (size_t)(b * 512 + ebase + e) * 512 + l0 + ll;
    p += EN[idx] * DE[idx];
  }
  red[g][ll] = p;
  __syncthreads();
  if (t < 64) {
    float s = red[0][t] + red[1][t] + red[2][t] + red[3][t];
    float val = __expf(INV_TAU * s) / down[r0 + t];
#pragma unroll
    for (int m = 1; m <= 32; m <<= 1) val += __shfl_xor(val, m);
    if (t == 0) atomicAdd(out, val);
  }
}

extern "C" void kernel_launch(void* const* d_in, const int* in_sizes, int n_in,
                              void* d_out, int out_size, void* d_ws, size_t ws_size,
                              hipStream_t stream) {
  const float* EN = (const float*)d_in[0];
  const float* DE = (const float*)d_in[1];
  const float* M  = (const float*)d_in[2];

  // ws layout: down[2048] f32 | A16 [2048*512] f16 | B16 [32000*512] f16
  float* down = (float*)d_ws;
  f16* A16 = (f16*)((char*)d_ws + 8192);
  f16* B16 = (f16*)((char*)d_ws + 8192 + (size_t)RDIM * EDIM * 2);
  const size_t need = 8192 + (size_t)RDIM * EDIM * 2 + (size_t)VDIM * EDIM * 2;

  hipMemsetAsync(d_out, 0, sizeof(float), stream);
  if (ws_size < need) return;
  hipMemsetAsync(d_ws, 0, RDIM * sizeof(float), stream);

  cvtA_kernel<<<dim3(8, 8, 4), 256, 0, stream>>>(DE, A16);
  cvtM_kernel<<<2048, 256, 0, stream>>>(M, B16);
  gemm_kernel<<<4000, 256, 0, stream>>>(A16, B16, down);
  finalize_kernel<<<32, 256, 0, stream>>>(EN, DE, down, (float*)d_out);
}